// Round 1
// baseline (168.061 us; speedup 1.0000x reference)
//
#include <hip/hip_runtime.h>

#define B_DIM 16
#define T_RED 512
#define C_DIM 512
#define ROWS_PER_BLK 16
#define NXCD 8

typedef float vfloat4 __attribute__((ext_vector_type(4)));

// Inclusive block scan over 256 threads (4 waves). Ends with a barrier so
// wsum can be reused by a subsequent call; wsum[0..3] still hold the four
// per-wave totals afterwards (used to get the block total for free).
__device__ inline int block_scan256(int v, int* wsum /*>=4 ints LDS*/) {
    const int lane = threadIdx.x & 63;
    const int wid  = threadIdx.x >> 6;  // 0..3
    int s = v;
    #pragma unroll
    for (int off = 1; off < 64; off <<= 1) {
        int n = __shfl_up(s, off, 64);
        if (lane >= off) s += n;
    }
    if (lane == 63) wsum[wid] = s;
    __syncthreads();
    int add = 0;
    #pragma unroll
    for (int w = 0; w < 4; ++w)
        if (w < wid) add += wsum[w];
    int out = s + add;
    __syncthreads();  // protect wsum for reuse
    return out;
}

// Setup kernel: ONE block per batch computes compaction + cumsum once, then
// INVERTS the searchsorted: compacted row j owns t in [csum[j-1], csum[j]),
// so it scatters ls[t] = j directly (<=16 writes per row). Also writes the
// mask row and the ls = -1 invalid tail.
// grid = (B), block = 256.
__global__ __launch_bounds__(256) void build_ls(
        const int2* __restrict__ dur2,     // durations viewed as int2
        int* __restrict__ ls,              // [B][max_len] source row or -1
        float* __restrict__ out_mask,
        int max_len) {
    const int b   = blockIdx.x;
    const int tid = threadIdx.x;

    __shared__ int dcomp[T_RED];
    __shared__ int wsum[4];

    const int2 dd = dur2[b * (T_RED / 2) + tid];
    const int d0 = dd.x, d1 = dd.y;
    const int f0 = (d0 > 0) ? 1 : 0;
    const int f1 = (d1 > 0) ? 1 : 0;

    // Scan 1: stable-compaction positions.
    const int S1 = block_scan256(f0 + f1, wsum);
    const int excl = S1 - f0 - f1;
    dcomp[2 * tid]     = 0;
    dcomp[2 * tid + 1] = 0;
    __syncthreads();
    if (f0) dcomp[excl] = d0;
    if (f1) dcomp[excl + f0] = d1;
    __syncthreads();

    // Scan 2: inclusive cumsum of compacted durations.
    const int c0 = dcomp[2 * tid];
    const int c1 = dcomp[2 * tid + 1];
    const int S2 = block_scan256(c0 + c1, wsum);
    // Block total = sum of the 4 wave totals (still live in wsum).
    const int total = wsum[0] + wsum[1] + wsum[2] + wsum[3];

    int* lsb = ls + (size_t)b * max_len;

    // Inverse scatter: compacted row (2*tid) covers [S2-c1-c0, S2-c1),
    // compacted row (2*tid+1) covers [S2-c1, S2). Reference gathers
    // pooled_x at the COMPACTED index (its seg indexes csum directly).
    const int st0 = S2 - c1 - c0;
    for (int k = 0; k < c0; ++k) lsb[st0 + k] = 2 * tid;
    const int st1 = S2 - c1;
    for (int k = 0; k < c1; ++k) lsb[st1 + k] = 2 * tid + 1;

    // Invalid tail: t in [total, max_len) -> no source, zero row.
    for (int t = total + tid; t < max_len; t += 256) lsb[t] = -1;

    // Mask row.
    float* mb = out_mask + (size_t)b * max_len;
    for (int t = tid; t < max_len; t += 256) mb[t] = (t < total) ? 0.0f : 1.0f;
}

// Main kernel: pure gather + streaming store. No LDS, no barriers.
// grid = (blk_per_b * B) 1-D with bijective XCD swizzle, block = 256.
__global__ __launch_bounds__(256) void gather_rows(
        const vfloat4* __restrict__ x4,
        const int* __restrict__ ls,
        vfloat4* __restrict__ out4,
        int max_len, int blk_per_b) {
    // Bijective XCD swizzle (m204): blocks on the same XCD get a contiguous
    // chunk of (batch, t) work -> source rows are fetched into one L2 once.
    const int nwg  = gridDim.x;
    const int orig = blockIdx.x;
    const int q = nwg / NXCD, r = nwg % NXCD;
    const int xcd = orig % NXCD, idx = orig / NXCD;
    const int wg  = (xcd < r ? xcd * (q + 1) : r * (q + 1) + (xcd - r) * q) + idx;

    const int b    = wg / blk_per_b;
    const int base = (wg % blk_per_b) * ROWS_PER_BLK;
    const int tid  = threadIdx.x;
    const int c4   = tid & 127;   // float4 column within the 512-float row
    const int half = tid >> 7;    // 0/1: which of each row-pair

    // Hoist the 8 source-row ids (wave-uniform loads, L1/L2 broadcast hits).
    const int* lsb = ls + (size_t)b * max_len + base;
    int srcs[8];
    #pragma unroll
    for (int p = 0; p < 8; ++p) {
        const int t = base + 2 * p + half;
        srcs[p] = (t < max_len) ? lsb[2 * p + half] : -1;
    }

    const vfloat4* xb = x4 + (size_t)b * T_RED * (C_DIM / 4);
    vfloat4* ob = out4 + ((size_t)b * max_len + base) * (C_DIM / 4);

    #pragma unroll
    for (int p = 0; p < 8; ++p) {
        const int t = base + 2 * p + half;
        if (t < max_len) {
            vfloat4 v = (vfloat4)(0.0f);
            const int s = srcs[p];
            if (s >= 0) v = xb[(size_t)s * (C_DIM / 4) + c4];
            __builtin_nontemporal_store(
                v, &ob[(size_t)(2 * p + half) * (C_DIM / 4) + c4]);
        }
    }
}

// ---------------------------------------------------------------------------
// Fallback: previous verified fused kernel (used only if d_ws is too small).
// ---------------------------------------------------------------------------
__global__ __launch_bounds__(256) void scatter_fused(
        const vfloat4* __restrict__ x4,
        const int2* __restrict__ dur2,
        vfloat4* __restrict__ out4,
        float* __restrict__ out_mask,
        int max_len) {
    const int b    = blockIdx.y;
    const int base = blockIdx.x * ROWS_PER_BLK;
    const int tid  = threadIdx.x;

    __shared__ int dcomp[T_RED];
    __shared__ int csum[T_RED];
    __shared__ int wsum[4];
    __shared__ int ls[ROWS_PER_BLK];

    const int2 dd = dur2[b * (T_RED / 2) + tid];
    const int d0 = dd.x, d1 = dd.y;
    const int f0 = (d0 > 0) ? 1 : 0;
    const int f1 = (d1 > 0) ? 1 : 0;

    const int S1 = block_scan256(f0 + f1, wsum);
    const int excl = S1 - f0 - f1;
    dcomp[2 * tid]     = 0;
    dcomp[2 * tid + 1] = 0;
    __syncthreads();
    if (f0) dcomp[excl] = d0;
    if (f1) dcomp[excl + f0] = d1;
    __syncthreads();

    const int c0 = dcomp[2 * tid];
    const int c1 = dcomp[2 * tid + 1];
    const int S2 = block_scan256(c0 + c1, wsum);
    csum[2 * tid]     = S2 - c1;
    csum[2 * tid + 1] = S2;
    __syncthreads();

    const int total = csum[T_RED - 1];

    if (tid < ROWS_PER_BLK) {
        const int t = base + tid;
        int src = -1;
        if (t < max_len && t < total) {
            int idx = 0;
            #pragma unroll
            for (int w = 256; w >= 1; w >>= 1) {
                const int cand = idx + w;
                if (cand <= T_RED && csum[cand - 1] <= t) idx = cand;
            }
            const int seg = (idx < T_RED - 1) ? idx : (T_RED - 1);
            src = b * T_RED + seg;
        }
        if (t < max_len) {
            ls[tid] = src;
            out_mask[(size_t)b * max_len + t] = (src >= 0) ? 0.0f : 1.0f;
        }
    }
    __syncthreads();

    const int c4   = tid & 127;
    const int half = tid >> 7;
    #pragma unroll
    for (int p = 0; p < 8; ++p) {
        const int lr = 2 * p + half;
        const int t  = base + lr;
        if (t < max_len) {
            const int s = ls[lr];
            vfloat4 v = (vfloat4)(0.0f);
            if (s >= 0) v = x4[(size_t)s * (C_DIM / 4) + c4];
            __builtin_nontemporal_store(
                v, &out4[((size_t)b * max_len + t) * (C_DIM / 4) + c4]);
        }
    }
}

extern "C" void kernel_launch(void* const* d_in, const int* in_sizes, int n_in,
                              void* d_out, int out_size, void* d_ws, size_t ws_size,
                              hipStream_t stream) {
    const float* pooled_x  = (const float*)d_in[0];
    const int*   durations = (const int*)d_in[1];

    // out_size = B*max_len*C + B*max_len  ->  max_len = out_size / (B*(C+1))
    const int max_len = out_size / (B_DIM * (C_DIM + 1));

    float* out_x    = (float*)d_out;
    float* out_mask = out_x + (size_t)B_DIM * max_len * C_DIM;

    const size_t ls_bytes = (size_t)B_DIM * max_len * sizeof(int);

    if (d_ws != nullptr && ws_size >= ls_bytes) {
        int* ls = (int*)d_ws;
        build_ls<<<dim3(B_DIM), dim3(256), 0, stream>>>(
            (const int2*)durations, ls, out_mask, max_len);

        const int blk_per_b = (max_len + ROWS_PER_BLK - 1) / ROWS_PER_BLK;
        gather_rows<<<dim3(blk_per_b * B_DIM), dim3(256), 0, stream>>>(
            (const vfloat4*)pooled_x, ls, (vfloat4*)out_x, max_len, blk_per_b);
    } else {
        // Safety fallback: previous verified fused kernel.
        dim3 grid((max_len + ROWS_PER_BLK - 1) / ROWS_PER_BLK, B_DIM);
        scatter_fused<<<grid, dim3(256), 0, stream>>>(
            (const vfloat4*)pooled_x, (const int2*)durations,
            (vfloat4*)out_x, out_mask, max_len);
    }
}

// Round 2
// 163.621 us; speedup vs baseline: 1.0271x; 1.0271x over previous
//
#include <hip/hip_runtime.h>

#define B_DIM 16
#define T_RED 512
#define C_DIM 512
#define ROWS_PER_BLK 16
#define NXCD 8
#define MAX_ML_PAD 20480   // static per-batch ls capacity (structural max_len <= 8192)

typedef float vfloat4 __attribute__((ext_vector_type(4)));

// Static segment-index table: [B][ml_pad], value = source row in pooled_x or -1.
// Rewritten in full by build_ls every invocation (no cross-iteration state).
__device__ int g_ls[B_DIM * MAX_ML_PAD];

// Inclusive block scan over 256 threads (4 waves). Ends with a barrier so
// wsum can be reused; wsum[0..3] still hold the four per-wave totals after.
__device__ inline int block_scan256(int v, int* wsum /*>=4 ints LDS*/) {
    const int lane = threadIdx.x & 63;
    const int wid  = threadIdx.x >> 6;  // 0..3
    int s = v;
    #pragma unroll
    for (int off = 1; off < 64; off <<= 1) {
        int n = __shfl_up(s, off, 64);
        if (lane >= off) s += n;
    }
    if (lane == 63) wsum[wid] = s;
    __syncthreads();
    int add = 0;
    #pragma unroll
    for (int w = 0; w < 4; ++w)
        if (w < wid) add += wsum[w];
    int out = s + add;
    __syncthreads();  // protect wsum for reuse
    return out;
}

// One block per batch: compaction + cumsum once, then INVERT the
// searchsorted: compacted row j owns t in [csum[j-1], csum[j]) and scatters
// g_ls[t] = j directly. Tail [total, ml_pad) gets -1 so the gather kernel can
// read g_ls unconditionally. Also writes the mask row.
// grid = (B), block = 256.
__global__ __launch_bounds__(256) void build_ls(
        const int2* __restrict__ dur2,     // durations viewed as int2
        float* __restrict__ out_mask,
        int max_len, int ml_pad) {
    const int b   = blockIdx.x;
    const int tid = threadIdx.x;

    __shared__ int dcomp[T_RED];
    __shared__ int wsum[4];

    const int2 dd = dur2[b * (T_RED / 2) + tid];
    const int d0 = dd.x, d1 = dd.y;
    const int f0 = (d0 > 0) ? 1 : 0;
    const int f1 = (d1 > 0) ? 1 : 0;

    // Scan 1: stable-compaction positions.
    const int S1 = block_scan256(f0 + f1, wsum);
    const int excl = S1 - f0 - f1;
    dcomp[2 * tid]     = 0;
    dcomp[2 * tid + 1] = 0;
    __syncthreads();
    if (f0) dcomp[excl] = d0;
    if (f1) dcomp[excl + f0] = d1;
    __syncthreads();

    // Scan 2: inclusive cumsum of compacted durations.
    const int c0 = dcomp[2 * tid];
    const int c1 = dcomp[2 * tid + 1];
    const int S2 = block_scan256(c0 + c1, wsum);
    const int total = wsum[0] + wsum[1] + wsum[2] + wsum[3];

    int* lsb = g_ls + (size_t)b * ml_pad;

    // Inverse scatter: compacted row (2*tid) covers [S2-c1-c0, S2-c1),
    // compacted row (2*tid+1) covers [S2-c1, S2). (Reference gathers
    // pooled_x at the COMPACTED index.)
    const int st0 = S2 - c1 - c0;
    for (int k = 0; k < c0; ++k) lsb[st0 + k] = 2 * tid;
    const int st1 = S2 - c1;
    for (int k = 0; k < c1; ++k) lsb[st1 + k] = 2 * tid + 1;

    // Invalid tail: covers the padded region too.
    for (int t = total + tid; t < ml_pad; t += 256) lsb[t] = -1;

    // Mask row.
    float* mb = out_mask + (size_t)b * max_len;
    for (int t = tid; t < max_len; t += 256) mb[t] = (t < total) ? 0.0f : 1.0f;
}

// Main kernel: pure gather + streaming store. No LDS, no barriers.
// Structured as: 8 unconditional index loads -> 8 unconditional gathered
// loads (ALL in flight, no per-iteration vmcnt(0) serialization) -> 8
// predicated nontemporal stores.
// grid = (blk_per_b * B) 1-D with bijective XCD swizzle, block = 256.
__global__ __launch_bounds__(256) void gather_rows(
        const vfloat4* __restrict__ x4,
        vfloat4* __restrict__ out4,
        int max_len, int ml_pad, int blk_per_b) {
    // Bijective XCD swizzle: blocks on the same XCD get a contiguous chunk
    // of (batch, t) work -> each XCD's L2 holds ~2 batches' pooled_x (2 MB).
    const int nwg  = gridDim.x;
    const int orig = blockIdx.x;
    const int q = nwg / NXCD, r = nwg % NXCD;
    const int xcd = orig % NXCD, idx = orig / NXCD;
    const int wg  = (xcd < r ? xcd * (q + 1) : r * (q + 1) + (xcd - r) * q) + idx;

    const int b    = wg / blk_per_b;
    const int base = (wg % blk_per_b) * ROWS_PER_BLK;
    const int tid  = threadIdx.x;
    const int c4   = tid & 127;   // float4 column within the 512-float row
    const int half = tid >> 7;    // 0/1: which of each row-pair

    // 8 unconditional index loads (padded table; wave-uniform -> broadcast).
    const int* lsb = g_ls + (size_t)b * ml_pad + base;
    int srcs[8];
    #pragma unroll
    for (int p = 0; p < 8; ++p) srcs[p] = lsb[2 * p + half];

    // 8 unconditional gathered row loads, all independent and in flight.
    // Invalid rows clamp to row 0 (always present) and are zeroed at store.
    const vfloat4* xb = x4 + (size_t)b * T_RED * (C_DIM / 4);
    vfloat4 v[8];
    #pragma unroll
    for (int p = 0; p < 8; ++p) {
        const int sc = (srcs[p] >= 0) ? srcs[p] : 0;
        v[p] = xb[(size_t)sc * (C_DIM / 4) + c4];
    }

    // 8 predicated streaming stores (fire-and-forget).
    vfloat4* ob = out4 + ((size_t)b * max_len + base) * (C_DIM / 4);
    #pragma unroll
    for (int p = 0; p < 8; ++p) {
        const int lr = 2 * p + half;
        const int t  = base + lr;
        if (t < max_len) {
            const vfloat4 vv = (srcs[p] >= 0) ? v[p] : (vfloat4)(0.0f);
            __builtin_nontemporal_store(
                vv, &ob[(size_t)lr * (C_DIM / 4) + c4]);
        }
    }
}

// ---------------------------------------------------------------------------
// Fallback (only if max_len exceeds static table capacity — structurally
// impossible for this problem, kept as insurance): previous verified kernel.
// ---------------------------------------------------------------------------
__global__ __launch_bounds__(256) void scatter_fused(
        const vfloat4* __restrict__ x4,
        const int2* __restrict__ dur2,
        vfloat4* __restrict__ out4,
        float* __restrict__ out_mask,
        int max_len) {
    const int b    = blockIdx.y;
    const int base = blockIdx.x * ROWS_PER_BLK;
    const int tid  = threadIdx.x;

    __shared__ int dcomp[T_RED];
    __shared__ int csum[T_RED];
    __shared__ int wsum[4];
    __shared__ int ls[ROWS_PER_BLK];

    const int2 dd = dur2[b * (T_RED / 2) + tid];
    const int d0 = dd.x, d1 = dd.y;
    const int f0 = (d0 > 0) ? 1 : 0;
    const int f1 = (d1 > 0) ? 1 : 0;

    const int S1 = block_scan256(f0 + f1, wsum);
    const int excl = S1 - f0 - f1;
    dcomp[2 * tid]     = 0;
    dcomp[2 * tid + 1] = 0;
    __syncthreads();
    if (f0) dcomp[excl] = d0;
    if (f1) dcomp[excl + f0] = d1;
    __syncthreads();

    const int c0 = dcomp[2 * tid];
    const int c1 = dcomp[2 * tid + 1];
    const int S2 = block_scan256(c0 + c1, wsum);
    csum[2 * tid]     = S2 - c1;
    csum[2 * tid + 1] = S2;
    __syncthreads();

    const int total = csum[T_RED - 1];

    if (tid < ROWS_PER_BLK) {
        const int t = base + tid;
        int src = -1;
        if (t < max_len && t < total) {
            int idx = 0;
            #pragma unroll
            for (int w = 256; w >= 1; w >>= 1) {
                const int cand = idx + w;
                if (cand <= T_RED && csum[cand - 1] <= t) idx = cand;
            }
            const int seg = (idx < T_RED - 1) ? idx : (T_RED - 1);
            src = b * T_RED + seg;
        }
        if (t < max_len) {
            ls[tid] = src;
            out_mask[(size_t)b * max_len + t] = (src >= 0) ? 0.0f : 1.0f;
        }
    }
    __syncthreads();

    const int c4   = tid & 127;
    const int half = tid >> 7;
    #pragma unroll
    for (int p = 0; p < 8; ++p) {
        const int lr = 2 * p + half;
        const int t  = base + lr;
        if (t < max_len) {
            const int s = ls[lr];
            vfloat4 v = (vfloat4)(0.0f);
            if (s >= 0) v = x4[(size_t)s * (C_DIM / 4) + c4];
            __builtin_nontemporal_store(
                v, &out4[((size_t)b * max_len + t) * (C_DIM / 4) + c4]);
        }
    }
}

extern "C" void kernel_launch(void* const* d_in, const int* in_sizes, int n_in,
                              void* d_out, int out_size, void* d_ws, size_t ws_size,
                              hipStream_t stream) {
    const float* pooled_x  = (const float*)d_in[0];
    const int*   durations = (const int*)d_in[1];

    // out_size = B*max_len*C + B*max_len  ->  max_len = out_size / (B*(C+1))
    const int max_len = out_size / (B_DIM * (C_DIM + 1));
    const int ml_pad  = (max_len + ROWS_PER_BLK - 1) & ~(ROWS_PER_BLK - 1);

    float* out_x    = (float*)d_out;
    float* out_mask = out_x + (size_t)B_DIM * max_len * C_DIM;

    if (ml_pad <= MAX_ML_PAD) {
        build_ls<<<dim3(B_DIM), dim3(256), 0, stream>>>(
            (const int2*)durations, out_mask, max_len, ml_pad);

        const int blk_per_b = ml_pad / ROWS_PER_BLK;
        gather_rows<<<dim3(blk_per_b * B_DIM), dim3(256), 0, stream>>>(
            (const vfloat4*)pooled_x, (vfloat4*)out_x, max_len, ml_pad, blk_per_b);
    } else {
        // Insurance only.
        dim3 grid((max_len + ROWS_PER_BLK - 1) / ROWS_PER_BLK, B_DIM);
        scatter_fused<<<grid, dim3(256), 0, stream>>>(
            (const vfloat4*)pooled_x, (const int2*)durations,
            (vfloat4*)out_x, out_mask, max_len);
    }
}

// Round 3
// 157.461 us; speedup vs baseline: 1.0673x; 1.0391x over previous
//
#include <hip/hip_runtime.h>

#define B_DIM 16
#define T_RED 512
#define C_DIM 512
#define ROWS_PER_BLK 16
#define NXCD 8
#define MAX_ML_PAD 20480   // static per-batch ls capacity (structural max_len <= 8192)

typedef float vfloat4 __attribute__((ext_vector_type(4)));

// Static segment-index table: [B][ml_pad], value = source row in pooled_x or -1.
// Rewritten in full by build_ls every invocation (no cross-iteration state).
__device__ int g_ls[B_DIM * MAX_ML_PAD];

// Inclusive block scan over 256 threads (4 waves). Ends with a barrier so
// wsum can be reused; wsum[0..3] still hold the four per-wave totals after.
__device__ inline int block_scan256(int v, int* wsum /*>=4 ints LDS*/) {
    const int lane = threadIdx.x & 63;
    const int wid  = threadIdx.x >> 6;  // 0..3
    int s = v;
    #pragma unroll
    for (int off = 1; off < 64; off <<= 1) {
        int n = __shfl_up(s, off, 64);
        if (lane >= off) s += n;
    }
    if (lane == 63) wsum[wid] = s;
    __syncthreads();
    int add = 0;
    #pragma unroll
    for (int w = 0; w < 4; ++w)
        if (w < wid) add += wsum[w];
    int out = s + add;
    __syncthreads();  // protect wsum for reuse
    return out;
}

// One block per batch: compaction + cumsum once, then INVERT the
// searchsorted: compacted row j owns t in [csum[j-1], csum[j]) and scatters
// g_ls[t] = j directly. Tail [total, ml_pad) gets -1 so the gather kernel can
// read g_ls unconditionally. Also writes the mask row.
// grid = (B), block = 256.
__global__ __launch_bounds__(256) void build_ls(
        const int2* __restrict__ dur2,     // durations viewed as int2
        float* __restrict__ out_mask,
        int max_len, int ml_pad) {
    const int b   = blockIdx.x;
    const int tid = threadIdx.x;

    __shared__ int dcomp[T_RED];
    __shared__ int wsum[4];

    const int2 dd = dur2[b * (T_RED / 2) + tid];
    const int d0 = dd.x, d1 = dd.y;
    const int f0 = (d0 > 0) ? 1 : 0;
    const int f1 = (d1 > 0) ? 1 : 0;

    // Scan 1: stable-compaction positions.
    const int S1 = block_scan256(f0 + f1, wsum);
    const int excl = S1 - f0 - f1;
    dcomp[2 * tid]     = 0;
    dcomp[2 * tid + 1] = 0;
    __syncthreads();
    if (f0) dcomp[excl] = d0;
    if (f1) dcomp[excl + f0] = d1;
    __syncthreads();

    // Scan 2: inclusive cumsum of compacted durations.
    const int c0 = dcomp[2 * tid];
    const int c1 = dcomp[2 * tid + 1];
    const int S2 = block_scan256(c0 + c1, wsum);
    const int total = wsum[0] + wsum[1] + wsum[2] + wsum[3];

    int* lsb = g_ls + (size_t)b * ml_pad;

    // Inverse scatter: compacted row (2*tid) covers [S2-c1-c0, S2-c1),
    // compacted row (2*tid+1) covers [S2-c1, S2). (Reference gathers
    // pooled_x at the COMPACTED index.)
    const int st0 = S2 - c1 - c0;
    for (int k = 0; k < c0; ++k) lsb[st0 + k] = 2 * tid;
    const int st1 = S2 - c1;
    for (int k = 0; k < c1; ++k) lsb[st1 + k] = 2 * tid + 1;

    // Invalid tail: covers the padded region too.
    for (int t = total + tid; t < ml_pad; t += 256) lsb[t] = -1;

    // Mask row.
    float* mb = out_mask + (size_t)b * max_len;
    for (int t = tid; t < max_len; t += 256) mb[t] = (t < total) ? 0.0f : 1.0f;
}

// Main kernel: pure gather + store. No LDS, no barriers.
// A/B vs round 2: PLAIN stores instead of nontemporal (single-variable test
// of the "nt bypass fights the freshly-poisoned dirty L2 lines" theory).
// grid = (blk_per_b * B) 1-D with bijective XCD swizzle, block = 256.
__global__ __launch_bounds__(256) void gather_rows(
        const vfloat4* __restrict__ x4,
        vfloat4* __restrict__ out4,
        int max_len, int ml_pad, int blk_per_b) {
    // Bijective XCD swizzle: blocks on the same XCD get a contiguous chunk
    // of (batch, t) work -> each XCD's L2 holds ~2 batches' pooled_x (2 MB).
    const int nwg  = gridDim.x;
    const int orig = blockIdx.x;
    const int q = nwg / NXCD, r = nwg % NXCD;
    const int xcd = orig % NXCD, idx = orig / NXCD;
    const int wg  = (xcd < r ? xcd * (q + 1) : r * (q + 1) + (xcd - r) * q) + idx;

    const int b    = wg / blk_per_b;
    const int base = (wg % blk_per_b) * ROWS_PER_BLK;
    const int tid  = threadIdx.x;
    const int c4   = tid & 127;   // float4 column within the 512-float row
    const int half = tid >> 7;    // 0/1: which of each row-pair

    // 8 unconditional index loads (padded table; wave-uniform -> broadcast).
    const int* lsb = g_ls + (size_t)b * ml_pad + base;
    int srcs[8];
    #pragma unroll
    for (int p = 0; p < 8; ++p) srcs[p] = lsb[2 * p + half];

    // 8 unconditional gathered row loads, all independent and in flight.
    // Invalid rows clamp to row 0 (always present) and are zeroed at store.
    const vfloat4* xb = x4 + (size_t)b * T_RED * (C_DIM / 4);
    vfloat4 v[8];
    #pragma unroll
    for (int p = 0; p < 8; ++p) {
        const int sc = (srcs[p] >= 0) ? srcs[p] : 0;
        v[p] = xb[(size_t)sc * (C_DIM / 4) + c4];
    }

    // 8 predicated PLAIN stores (absorb into L2; lazy writeback).
    vfloat4* ob = out4 + ((size_t)b * max_len + base) * (C_DIM / 4);
    #pragma unroll
    for (int p = 0; p < 8; ++p) {
        const int lr = 2 * p + half;
        const int t  = base + lr;
        if (t < max_len) {
            const vfloat4 vv = (srcs[p] >= 0) ? v[p] : (vfloat4)(0.0f);
            ob[(size_t)lr * (C_DIM / 4) + c4] = vv;
        }
    }
}

// ---------------------------------------------------------------------------
// Fallback (only if max_len exceeds static table capacity — structurally
// impossible for this problem, kept as insurance): previous verified kernel.
// ---------------------------------------------------------------------------
__global__ __launch_bounds__(256) void scatter_fused(
        const vfloat4* __restrict__ x4,
        const int2* __restrict__ dur2,
        vfloat4* __restrict__ out4,
        float* __restrict__ out_mask,
        int max_len) {
    const int b    = blockIdx.y;
    const int base = blockIdx.x * ROWS_PER_BLK;
    const int tid  = threadIdx.x;

    __shared__ int dcomp[T_RED];
    __shared__ int csum[T_RED];
    __shared__ int wsum[4];
    __shared__ int ls[ROWS_PER_BLK];

    const int2 dd = dur2[b * (T_RED / 2) + tid];
    const int d0 = dd.x, d1 = dd.y;
    const int f0 = (d0 > 0) ? 1 : 0;
    const int f1 = (d1 > 0) ? 1 : 0;

    const int S1 = block_scan256(f0 + f1, wsum);
    const int excl = S1 - f0 - f1;
    dcomp[2 * tid]     = 0;
    dcomp[2 * tid + 1] = 0;
    __syncthreads();
    if (f0) dcomp[excl] = d0;
    if (f1) dcomp[excl + f0] = d1;
    __syncthreads();

    const int c0 = dcomp[2 * tid];
    const int c1 = dcomp[2 * tid + 1];
    const int S2 = block_scan256(c0 + c1, wsum);
    csum[2 * tid]     = S2 - c1;
    csum[2 * tid + 1] = S2;
    __syncthreads();

    const int total = csum[T_RED - 1];

    if (tid < ROWS_PER_BLK) {
        const int t = base + tid;
        int src = -1;
        if (t < max_len && t < total) {
            int idx = 0;
            #pragma unroll
            for (int w = 256; w >= 1; w >>= 1) {
                const int cand = idx + w;
                if (cand <= T_RED && csum[cand - 1] <= t) idx = cand;
            }
            const int seg = (idx < T_RED - 1) ? idx : (T_RED - 1);
            src = b * T_RED + seg;
        }
        if (t < max_len) {
            ls[tid] = src;
            out_mask[(size_t)b * max_len + t] = (src >= 0) ? 0.0f : 1.0f;
        }
    }
    __syncthreads();

    const int c4   = tid & 127;
    const int half = tid >> 7;
    #pragma unroll
    for (int p = 0; p < 8; ++p) {
        const int lr = 2 * p + half;
        const int t  = base + lr;
        if (t < max_len) {
            const int s = ls[lr];
            vfloat4 v = (vfloat4)(0.0f);
            if (s >= 0) v = x4[(size_t)s * (C_DIM / 4) + c4];
            out4[((size_t)b * max_len + t) * (C_DIM / 4) + c4] = v;
        }
    }
}

extern "C" void kernel_launch(void* const* d_in, const int* in_sizes, int n_in,
                              void* d_out, int out_size, void* d_ws, size_t ws_size,
                              hipStream_t stream) {
    const float* pooled_x  = (const float*)d_in[0];
    const int*   durations = (const int*)d_in[1];

    // out_size = B*max_len*C + B*max_len  ->  max_len = out_size / (B*(C+1))
    const int max_len = out_size / (B_DIM * (C_DIM + 1));
    const int ml_pad  = (max_len + ROWS_PER_BLK - 1) & ~(ROWS_PER_BLK - 1);

    float* out_x    = (float*)d_out;
    float* out_mask = out_x + (size_t)B_DIM * max_len * C_DIM;

    if (ml_pad <= MAX_ML_PAD) {
        build_ls<<<dim3(B_DIM), dim3(256), 0, stream>>>(
            (const int2*)durations, out_mask, max_len, ml_pad);

        const int blk_per_b = ml_pad / ROWS_PER_BLK;
        gather_rows<<<dim3(blk_per_b * B_DIM), dim3(256), 0, stream>>>(
            (const vfloat4*)pooled_x, (vfloat4*)out_x, max_len, ml_pad, blk_per_b);
    } else {
        // Insurance only.
        dim3 grid((max_len + ROWS_PER_BLK - 1) / ROWS_PER_BLK, B_DIM);
        scatter_fused<<<grid, dim3(256), 0, stream>>>(
            (const vfloat4*)pooled_x, (const int2*)durations,
            (vfloat4*)out_x, out_mask, max_len);
    }
}